// Round 5
// baseline (535.108 us; speedup 1.0000x reference)
//
#include <hip/hip_runtime.h>

// 2-layer tanh RNN, T=2048, B=4096, I=3, H=5. f32 storage.
//
// R10: R5..R9 fit cy/step ~ 5.5-7 x (instr/step/wave); per-wave instr
// count is algorithm-locked at ~50 for any single-wave lane-slicing
// (dots+4 tanh+bcast+mem), so all variants plateau at ~355 cy/step.
// Escape: TWO waves per chain group (producer/consumer layer split).
//   wave A: layer-0 recurrence only (~24 instr/step), writes h0 blocks
//           of TBLK=8 steps into an LDS ring (double-buffered).
//   wave B: layer-1 recurrence + out stores (~29 instr/step), consumes
//           the ring one super-iteration behind A.
// __syncthreads() once per super-iter (both waves, outside role branch).
// B prefetches next step's h0 one step ahead -> LDS latency off-path
// except once per 8 steps. Compute is instruction-mirrored from R9
// (same pk order, same tanh) -> absmax must stay 0.00390625.

typedef float v2f __attribute__((ext_vector_type(2)));

#define SEQ_T 2048
#define BATCH 4096
#define ISZ 3
#define HSZ 5
#define TBLK 8                    // steps per super-iteration / ring buffer
#define NSUP (SEQ_T / TBLK)       // 256
#define XSTRIDE (BATCH * ISZ)
#define OSTRIDE (BATCH * HSZ)

template<int K>
__device__ __forceinline__ float qbcast(float v) {
    return __int_as_float(__builtin_amdgcn_mov_dpp(
        __float_as_int(v), K * 0x55, 0xF, 0xF, false));
}
// input pre-scaled by S = 2*log2(e): tanh(z) = 1 - 2*rcp(1 + exp2(S*z))
__device__ __forceinline__ float tanh_fast(float a) {
    float e = __builtin_amdgcn_exp2f(a);
    return fmaf(-2.0f, __builtin_amdgcn_rcpf(1.0f + e), 1.0f);
}
__device__ __forceinline__ v2f vsplat(float s) { return (v2f){s, s}; }
__device__ __forceinline__ v2f vfma(float s, v2f w, v2f a) {
    return __builtin_elementwise_fma(vsplat(s), w, a);  // v_pk_fma_f32
}

__global__ __launch_bounds__(128, 1)
void rnn2_ppl(const float* __restrict__ x, const float* __restrict__ hx,
              const float* __restrict__ w_ih0, const float* __restrict__ w_hh0,
              const float* __restrict__ b_ih0, const float* __restrict__ b_hh0,
              const float* __restrict__ w_ih1, const float* __restrict__ w_hh1,
              const float* __restrict__ b_ih1, const float* __restrict__ b_hh1,
              float* __restrict__ out)
{
    // ring[buf][step][chain_local][10]: slots [ja*2]=unit ja, [ja*2+1]=unit 4.
    // row stride 10 floats (40B): keeps b64 writes 8B-aligned, de-conflicts
    // B's broadcast reads across chain_local.
    __shared__ float ring[2][TBLK][16][10];

    const int tid  = threadIdx.x;
    const int wid  = tid >> 6;                      // 0 = layer0, 1 = layer1
    const int lane = tid & 63;
    const int cl   = lane >> 2;                     // chain-local 0..15
    const int ja   = lane & 3;                      // slot-A unit; slot B = 4
    const int c    = blockIdx.x * 16 + cl;          // chain id 0..4095
    const float S  = 2.8853900817779268f;

    // ---- weight pairs (ja-row, 4-row), pre-scaled by S ----
    const v2f bias0p = (v2f){ S * (b_ih0[ja] + b_hh0[ja]), S * (b_ih0[4] + b_hh0[4]) };
    const v2f bias1p = (v2f){ S * (b_ih1[ja] + b_hh1[ja]), S * (b_ih1[4] + b_hh1[4]) };
#define LW(W, k, n)  (v2f){ S * W[ja * (n) + (k)], S * W[4 * (n) + (k)] }
    const v2f wi0p0 = LW(w_ih0, 0, ISZ), wi0p1 = LW(w_ih0, 1, ISZ), wi0p2 = LW(w_ih0, 2, ISZ);
    const v2f wh0p0 = LW(w_hh0, 0, HSZ), wh0p1 = LW(w_hh0, 1, HSZ), wh0p2 = LW(w_hh0, 2, HSZ),
              wh0p3 = LW(w_hh0, 3, HSZ), wh0p4 = LW(w_hh0, 4, HSZ);
    const v2f wi1p0 = LW(w_ih1, 0, HSZ), wi1p1 = LW(w_ih1, 1, HSZ), wi1p2 = LW(w_ih1, 2, HSZ),
              wi1p3 = LW(w_ih1, 3, HSZ), wi1p4 = LW(w_ih1, 4, HSZ);
    const v2f wh1p0 = LW(w_hh1, 0, HSZ), wh1p1 = LW(w_hh1, 1, HSZ), wh1p2 = LW(w_hh1, 2, HSZ),
              wh1p3 = LW(w_hh1, 3, HSZ), wh1p4 = LW(w_hh1, 4, HSZ);
#undef LW

    // ---- state (wave A uses h0b*, wave B uses h1b*) ----
    float h0b0 = hx[(size_t)c * HSZ + 0], h0b1 = hx[(size_t)c * HSZ + 1],
          h0b2 = hx[(size_t)c * HSZ + 2], h0b3 = hx[(size_t)c * HSZ + 3],
          h0b4 = hx[(size_t)c * HSZ + 4];
    const size_t hb1 = (size_t)BATCH * HSZ + (size_t)c * HSZ;
    float h1b0 = hx[hb1 + 0], h1b1 = hx[hb1 + 1], h1b2 = hx[hb1 + 2],
          h1b3 = hx[hb1 + 3], h1b4 = hx[hb1 + 4];

    // ---- x pipeline (wave A): depth TBLK=8, 24 named floats ----
    unsigned xoff = (unsigned)c * ISZ;
    float x0a = x[xoff + 0*XSTRIDE], x0b = x[xoff + 0*XSTRIDE + 1], x0c = x[xoff + 0*XSTRIDE + 2];
    float x1a = x[xoff + 1*XSTRIDE], x1b = x[xoff + 1*XSTRIDE + 1], x1c = x[xoff + 1*XSTRIDE + 2];
    float x2a = x[xoff + 2*XSTRIDE], x2b = x[xoff + 2*XSTRIDE + 1], x2c = x[xoff + 2*XSTRIDE + 2];
    float x3a = x[xoff + 3*XSTRIDE], x3b = x[xoff + 3*XSTRIDE + 1], x3c = x[xoff + 3*XSTRIDE + 2];
    float x4a = x[xoff + 4*XSTRIDE], x4b = x[xoff + 4*XSTRIDE + 1], x4c = x[xoff + 4*XSTRIDE + 2];
    float x5a = x[xoff + 5*XSTRIDE], x5b = x[xoff + 5*XSTRIDE + 1], x5c = x[xoff + 5*XSTRIDE + 2];
    float x6a = x[xoff + 6*XSTRIDE], x6b = x[xoff + 6*XSTRIDE + 1], x6c = x[xoff + 6*XSTRIDE + 2];
    float x7a = x[xoff + 7*XSTRIDE], x7b = x[xoff + 7*XSTRIDE + 1], x7c = x[xoff + 7*XSTRIDE + 2];
    xoff += TBLK * XSTRIDE;

    // ---- output offsets (wave B) ----
    unsigned ooffA = (unsigned)c * HSZ + (unsigned)ja;
    unsigned ooffB = (unsigned)c * HSZ + 4u;

// wave A: one layer-0 step; consume (XV0..2), refill from x[t+8]
#define STEP0(TT, XV0, XV1, XV2)                                           \
    {                                                                      \
        const float xv0 = XV0, xv1 = XV1, xv2 = XV2;                       \
        XV0 = x[xoff]; XV1 = x[xoff + 1]; XV2 = x[xoff + 2];               \
        xoff += XSTRIDE;                                                   \
        v2f a = bias0p, cc = (v2f){0.0f, 0.0f};                            \
        a  = vfma(xv0,  wi0p0, a);                                         \
        cc = vfma(xv1,  wi0p1, cc);                                        \
        a  = vfma(xv2,  wi0p2, a);                                         \
        cc = vfma(h0b0, wh0p0, cc);                                        \
        a  = vfma(h0b1, wh0p1, a);                                         \
        cc = vfma(h0b2, wh0p2, cc);                                        \
        a  = vfma(h0b3, wh0p3, a);                                         \
        cc = vfma(h0b4, wh0p4, cc);                                        \
        a = a + cc;                                                        \
        const float nA = tanh_fast(a.x);                                   \
        const float nB = tanh_fast(a.y);                                   \
        h0b0 = qbcast<0>(nA);                                              \
        h0b1 = qbcast<1>(nA);                                              \
        h0b2 = qbcast<2>(nA);                                              \
        h0b3 = qbcast<3>(nA);                                              \
        h0b4 = nB;                                                         \
        *(v2f*)&wr[TT][cl][ja * 2] = (v2f){nA, nB};                        \
    }

// wave B: one layer-1 step; consume g0..g4 = h0(t); prefetch t+1 if DOPRE
#define STEP1(TT, DOPRE)                                                   \
    {                                                                      \
        const float u0 = g0, u1 = g1, u2 = g2, u3 = g3, u4 = g4;           \
        if (DOPRE) {                                                       \
            const float* q = &rd[(TT) + 1][cl][0];                         \
            g0 = q[0]; g1 = q[2]; g2 = q[4]; g3 = q[6]; g4 = q[1];         \
        }                                                                  \
        v2f d = bias1p, ee = (v2f){0.0f, 0.0f};                            \
        d  = vfma(u0,   wi1p0, d);                                         \
        ee = vfma(u1,   wi1p1, ee);                                        \
        d  = vfma(u2,   wi1p2, d);                                         \
        ee = vfma(u3,   wi1p3, ee);                                        \
        d  = vfma(u4,   wi1p4, d);                                         \
        ee = vfma(h1b0, wh1p0, ee);                                        \
        d  = vfma(h1b1, wh1p1, d);                                         \
        ee = vfma(h1b2, wh1p2, ee);                                        \
        d  = vfma(h1b3, wh1p3, d);                                         \
        ee = vfma(h1b4, wh1p4, ee);                                        \
        d = d + ee;                                                        \
        const float nA = tanh_fast(d.x);                                   \
        const float nB = tanh_fast(d.y);                                   \
        out[ooffA] = nA;                                                   \
        out[ooffB] = nB;                                                   \
        ooffA += OSTRIDE;                                                  \
        ooffB += OSTRIDE;                                                  \
        h1b0 = qbcast<0>(nA);                                              \
        h1b1 = qbcast<1>(nA);                                              \
        h1b2 = qbcast<2>(nA);                                              \
        h1b3 = qbcast<3>(nA);                                              \
        h1b4 = nB;                                                         \
    }

    for (int si = 0; si <= NSUP; ++si) {
        __syncthreads();   // A's buffer (si-1) now visible to B
        if (wid == 0) {
            if (si < NSUP) {
                // last fill: rewind so prefetch re-reads in-bounds rows
                // (loaded values are never consumed)
                if (si == NSUP - 1) xoff -= (unsigned)(TBLK * XSTRIDE);
                float (*wr)[16][10] = ring[si & 1];
                STEP0(0, x0a, x0b, x0c)
                STEP0(1, x1a, x1b, x1c)
                STEP0(2, x2a, x2b, x2c)
                STEP0(3, x3a, x3b, x3c)
                STEP0(4, x4a, x4b, x4c)
                STEP0(5, x5a, x5b, x5c)
                STEP0(6, x6a, x6b, x6c)
                STEP0(7, x7a, x7b, x7c)
            }
        } else {
            if (si > 0) {
                float (*rd)[16][10] = ring[(si - 1) & 1];
                float g0, g1, g2, g3, g4;
                { const float* q = &rd[0][cl][0];
                  g0 = q[0]; g1 = q[2]; g2 = q[4]; g3 = q[6]; g4 = q[1]; }
                STEP1(0, 1)
                STEP1(1, 1)
                STEP1(2, 1)
                STEP1(3, 1)
                STEP1(4, 1)
                STEP1(5, 1)
                STEP1(6, 1)
                STEP1(7, 0)
            }
        }
    }
#undef STEP0
#undef STEP1

    // h_n = [h0_final, h1_final] after out[T,B,H]; quad-dup stores benign
    float* hn = out + (size_t)SEQ_T * BATCH * HSZ;
    if (wid == 0) {
        hn[(size_t)c * HSZ + 0] = h0b0;
        hn[(size_t)c * HSZ + 1] = h0b1;
        hn[(size_t)c * HSZ + 2] = h0b2;
        hn[(size_t)c * HSZ + 3] = h0b3;
        hn[(size_t)c * HSZ + 4] = h0b4;
    } else {
        hn[hb1 + 0] = h1b0;
        hn[hb1 + 1] = h1b1;
        hn[hb1 + 2] = h1b2;
        hn[hb1 + 3] = h1b3;
        hn[hb1 + 4] = h1b4;
    }
}

extern "C" void kernel_launch(void* const* d_in, const int* in_sizes, int n_in,
                              void* d_out, int out_size, void* d_ws, size_t ws_size,
                              hipStream_t stream) {
    // 256 blocks x 128 threads: 16 chains/block, wave0=layer0, wave1=layer1.
    rnn2_ppl<<<BATCH / 16, 128, 0, stream>>>(
        (const float*)d_in[0], (const float*)d_in[1],
        (const float*)d_in[2], (const float*)d_in[3],
        (const float*)d_in[4], (const float*)d_in[5],
        (const float*)d_in[6], (const float*)d_in[7],
        (const float*)d_in[8], (const float*)d_in[9],
        (float*)d_out);
}

// Round 6
// 446.034 us; speedup vs baseline: 1.1997x; 1.1997x over previous
//
#include <hip/hip_runtime.h>

// 2-layer tanh RNN, T=2048, B=4096, I=3, H=5. f32 storage.
//
// R11: R5..R10 post-mortems killed the bcast-latency, store-WAR, scratch,
// and issue-cadence theories. Surviving theory: IN-ORDER ISSUE serializes
// the L0 and L1 latency chains -- every dependent hop (fma, exp2, rcp,
// DPP) stalls the solo wave, and the independent work that could fill the
// bubble is BEHIND it in program order. Sum of serialized hops ~ 350 cy
// == measured W for R6/R7/R9; VALUBusy 17.6% (~62/352 issue cy) agrees.
// Fix: software-pipeline layer 1 one step behind layer 0 and hand-
// interleave the two dot chains + four tanh chains in program order.
// Body(t) = [L0-dot(t) || L1-dot(t-1)] (both read h0b = h0(t-1)), then
// 4 independent tanh evals, then both bcasts + store of h1(t-1).
// Instruction mix and per-chain accumulation order are IDENTICAL to R9
// (only program order changed) -> absmax must stay 0.00390625.
// Structure kept from R9: 4 lanes/chain (quad_perm bcast), pk dual-slot
// (lane ja owns unit ja, all lanes duplicate unit 4), depth-8 x pipeline
// in named regs, 32-bit offsets off uniform base.

typedef float v2f __attribute__((ext_vector_type(2)));

#define SEQ_T 2048
#define BATCH 4096
#define ISZ 3
#define HSZ 5
#define XSTRIDE (BATCH * ISZ)
#define OSTRIDE (BATCH * HSZ)

template<int K>
__device__ __forceinline__ float qbcast(float v) {
    return __int_as_float(__builtin_amdgcn_mov_dpp(
        __float_as_int(v), K * 0x55, 0xF, 0xF, false));
}
__device__ __forceinline__ v2f vsplat(float s) { return (v2f){s, s}; }
__device__ __forceinline__ v2f vfma(float s, v2f w, v2f a) {
    return __builtin_elementwise_fma(vsplat(s), w, a);  // v_pk_fma_f32
}

__global__ __launch_bounds__(64, 1)
void rnn2_swp(const float* __restrict__ x, const float* __restrict__ hx,
              const float* __restrict__ w_ih0, const float* __restrict__ w_hh0,
              const float* __restrict__ b_ih0, const float* __restrict__ b_hh0,
              const float* __restrict__ w_ih1, const float* __restrict__ w_hh1,
              const float* __restrict__ b_ih1, const float* __restrict__ b_hh1,
              float* __restrict__ out)
{
    const int tid = threadIdx.x;
    const int c   = (blockIdx.x * 64 + tid) >> 2;   // chain id, 0..4095
    const int ja  = tid & 3;                        // slot-A unit; slot B = 4
    const float S = 2.8853900817779268f;            // 2*log2(e)

    // ---- weight pairs (ja-row, 4-row), pre-scaled by S — all NAMED ----
    const v2f bias0p = (v2f){ S * (b_ih0[ja] + b_hh0[ja]), S * (b_ih0[4] + b_hh0[4]) };
    const v2f bias1p = (v2f){ S * (b_ih1[ja] + b_hh1[ja]), S * (b_ih1[4] + b_hh1[4]) };
#define LW(W, k, n)  (v2f){ S * W[ja * (n) + (k)], S * W[4 * (n) + (k)] }
    const v2f wi0p0 = LW(w_ih0, 0, ISZ), wi0p1 = LW(w_ih0, 1, ISZ), wi0p2 = LW(w_ih0, 2, ISZ);
    const v2f wh0p0 = LW(w_hh0, 0, HSZ), wh0p1 = LW(w_hh0, 1, HSZ), wh0p2 = LW(w_hh0, 2, HSZ),
              wh0p3 = LW(w_hh0, 3, HSZ), wh0p4 = LW(w_hh0, 4, HSZ);
    const v2f wi1p0 = LW(w_ih1, 0, HSZ), wi1p1 = LW(w_ih1, 1, HSZ), wi1p2 = LW(w_ih1, 2, HSZ),
              wi1p3 = LW(w_ih1, 3, HSZ), wi1p4 = LW(w_ih1, 4, HSZ);
    const v2f wh1p0 = LW(w_hh1, 0, HSZ), wh1p1 = LW(w_hh1, 1, HSZ), wh1p2 = LW(w_hh1, 2, HSZ),
              wh1p3 = LW(w_hh1, 3, HSZ), wh1p4 = LW(w_hh1, 4, HSZ);
#undef LW

    // ---- state: named scalars (index 4 is lane-local duplicate) ----
    float h0b0 = hx[(size_t)c * HSZ + 0], h0b1 = hx[(size_t)c * HSZ + 1],
          h0b2 = hx[(size_t)c * HSZ + 2], h0b3 = hx[(size_t)c * HSZ + 3],
          h0b4 = hx[(size_t)c * HSZ + 4];
    const size_t hb1 = (size_t)BATCH * HSZ + (size_t)c * HSZ;
    float h1b0 = hx[hb1 + 0], h1b1 = hx[hb1 + 1], h1b2 = hx[hb1 + 2],
          h1b3 = hx[hb1 + 3], h1b4 = hx[hb1 + 4];

    // ---- x pipeline: depth 8, 24 NAMED floats ----
    unsigned xoff = (unsigned)c * ISZ;
    float x0a = x[xoff + 0*XSTRIDE], x0b = x[xoff + 0*XSTRIDE + 1], x0c = x[xoff + 0*XSTRIDE + 2];
    float x1a = x[xoff + 1*XSTRIDE], x1b = x[xoff + 1*XSTRIDE + 1], x1c = x[xoff + 1*XSTRIDE + 2];
    float x2a = x[xoff + 2*XSTRIDE], x2b = x[xoff + 2*XSTRIDE + 1], x2c = x[xoff + 2*XSTRIDE + 2];
    float x3a = x[xoff + 3*XSTRIDE], x3b = x[xoff + 3*XSTRIDE + 1], x3c = x[xoff + 3*XSTRIDE + 2];
    float x4a = x[xoff + 4*XSTRIDE], x4b = x[xoff + 4*XSTRIDE + 1], x4c = x[xoff + 4*XSTRIDE + 2];
    float x5a = x[xoff + 5*XSTRIDE], x5b = x[xoff + 5*XSTRIDE + 1], x5c = x[xoff + 5*XSTRIDE + 2];
    float x6a = x[xoff + 6*XSTRIDE], x6b = x[xoff + 6*XSTRIDE + 1], x6c = x[xoff + 6*XSTRIDE + 2];
    float x7a = x[xoff + 7*XSTRIDE], x7b = x[xoff + 7*XSTRIDE + 1], x7c = x[xoff + 7*XSTRIDE + 2];
    xoff += 8 * XSTRIDE;

    unsigned ooffA = (unsigned)c * HSZ + (unsigned)ja;
    unsigned ooffB = (unsigned)c * HSZ + 4u;

// PAIR: L0-dot(t) interleaved with L1-dot(t-1); both read h0b = h0(t-1).
// Then 4 independent tanh evals, bcasts, store of h1(t-1).
// Per-chain accumulation order identical to R9.
#define PAIR(XV0, XV1, XV2, DOLOAD)                                        \
    {                                                                      \
        const float xv0 = XV0, xv1 = XV1, xv2 = XV2;                       \
        if (DOLOAD) {                                                      \
            XV0 = x[xoff]; XV1 = x[xoff + 1]; XV2 = x[xoff + 2];           \
            xoff += XSTRIDE;                                               \
        }                                                                  \
        v2f a = bias0p, cc = (v2f){0.0f, 0.0f};                            \
        v2f d = bias1p, ee = (v2f){0.0f, 0.0f};                            \
        a  = vfma(xv0,  wi0p0, a);                                         \
        d  = vfma(h0b0, wi1p0, d);                                         \
        cc = vfma(xv1,  wi0p1, cc);                                        \
        ee = vfma(h0b1, wi1p1, ee);                                        \
        a  = vfma(xv2,  wi0p2, a);                                         \
        d  = vfma(h0b2, wi1p2, d);                                         \
        cc = vfma(h0b0, wh0p0, cc);                                        \
        ee = vfma(h0b3, wi1p3, ee);                                        \
        a  = vfma(h0b1, wh0p1, a);                                         \
        d  = vfma(h0b4, wi1p4, d);                                         \
        cc = vfma(h0b2, wh0p2, cc);                                        \
        ee = vfma(h1b0, wh1p0, ee);                                        \
        a  = vfma(h0b3, wh0p3, a);                                         \
        d  = vfma(h1b1, wh1p1, d);                                         \
        cc = vfma(h0b4, wh0p4, cc);                                        \
        ee = vfma(h1b2, wh1p2, ee);                                        \
        a = a + cc;                                                        \
        d  = vfma(h1b3, wh1p3, d);                                         \
        ee = vfma(h1b4, wh1p4, ee);                                        \
        const float e0x = __builtin_amdgcn_exp2f(a.x);                     \
        const float e0y = __builtin_amdgcn_exp2f(a.y);                     \
        d = d + ee;                                                        \
        const float e1x = __builtin_amdgcn_exp2f(d.x);                     \
        const float e1y = __builtin_amdgcn_exp2f(d.y);                     \
        const float n0A = fmaf(-2.0f, __builtin_amdgcn_rcpf(1.0f + e0x), 1.0f); \
        const float n0B = fmaf(-2.0f, __builtin_amdgcn_rcpf(1.0f + e0y), 1.0f); \
        const float n1A = fmaf(-2.0f, __builtin_amdgcn_rcpf(1.0f + e1x), 1.0f); \
        const float n1B = fmaf(-2.0f, __builtin_amdgcn_rcpf(1.0f + e1y), 1.0f); \
        h0b0 = qbcast<0>(n0A);                                             \
        h0b1 = qbcast<1>(n0A);                                             \
        h0b2 = qbcast<2>(n0A);                                             \
        h0b3 = qbcast<3>(n0A);                                             \
        h0b4 = n0B;                                                        \
        out[ooffA] = n1A;                                                  \
        out[ooffB] = n1B;                                                  \
        ooffA += OSTRIDE;                                                  \
        ooffB += OSTRIDE;                                                  \
        h1b0 = qbcast<0>(n1A);                                             \
        h1b1 = qbcast<1>(n1A);                                             \
        h1b2 = qbcast<2>(n1A);                                             \
        h1b3 = qbcast<3>(n1A);                                             \
        h1b4 = n1B;                                                        \
    }

// L0-only (pipeline prologue, step 0)
#define P0ONLY(XV0, XV1, XV2)                                              \
    {                                                                      \
        const float xv0 = XV0, xv1 = XV1, xv2 = XV2;                       \
        XV0 = x[xoff]; XV1 = x[xoff + 1]; XV2 = x[xoff + 2];               \
        xoff += XSTRIDE;                                                   \
        v2f a = bias0p, cc = (v2f){0.0f, 0.0f};                            \
        a  = vfma(xv0,  wi0p0, a);                                         \
        cc = vfma(xv1,  wi0p1, cc);                                        \
        a  = vfma(xv2,  wi0p2, a);                                         \
        cc = vfma(h0b0, wh0p0, cc);                                        \
        a  = vfma(h0b1, wh0p1, a);                                         \
        cc = vfma(h0b2, wh0p2, cc);                                        \
        a  = vfma(h0b3, wh0p3, a);                                         \
        cc = vfma(h0b4, wh0p4, cc);                                        \
        a = a + cc;                                                        \
        const float e0x = __builtin_amdgcn_exp2f(a.x);                     \
        const float e0y = __builtin_amdgcn_exp2f(a.y);                     \
        const float n0A = fmaf(-2.0f, __builtin_amdgcn_rcpf(1.0f + e0x), 1.0f); \
        const float n0B = fmaf(-2.0f, __builtin_amdgcn_rcpf(1.0f + e0y), 1.0f); \
        h0b0 = qbcast<0>(n0A);                                             \
        h0b1 = qbcast<1>(n0A);                                             \
        h0b2 = qbcast<2>(n0A);                                             \
        h0b3 = qbcast<3>(n0A);                                             \
        h0b4 = n0B;                                                        \
    }

    // ---- prologue: P0(0); then pairs P0(1..7)|P1(0..6), all refilling ----
    P0ONLY(x0a, x0b, x0c)
    PAIR(x1a, x1b, x1c, 1)
    PAIR(x2a, x2b, x2c, 1)
    PAIR(x3a, x3b, x3c, 1)
    PAIR(x4a, x4b, x4c, 1)
    PAIR(x5a, x5b, x5c, 1)
    PAIR(x6a, x6b, x6c, 1)
    PAIR(x7a, x7b, x7c, 1)

    // ---- steady: blocks 1..254, P0(8b..8b+7)|P1(8b-1..8b+6), refilling ----
    for (int blk = 1; blk < SEQ_T / 8 - 1; ++blk) {
        PAIR(x0a, x0b, x0c, 1)
        PAIR(x1a, x1b, x1c, 1)
        PAIR(x2a, x2b, x2c, 1)
        PAIR(x3a, x3b, x3c, 1)
        PAIR(x4a, x4b, x4c, 1)
        PAIR(x5a, x5b, x5c, 1)
        PAIR(x6a, x6b, x6c, 1)
        PAIR(x7a, x7b, x7c, 1)
    }

    // ---- final block 255: steps 2040..2047, no refill (x fully consumed) ----
    PAIR(x0a, x0b, x0c, 0)
    PAIR(x1a, x1b, x1c, 0)
    PAIR(x2a, x2b, x2c, 0)
    PAIR(x3a, x3b, x3c, 0)
    PAIR(x4a, x4b, x4c, 0)
    PAIR(x5a, x5b, x5c, 0)
    PAIR(x6a, x6b, x6c, 0)
    PAIR(x7a, x7b, x7c, 0)

    // ---- epilogue: P1(2047) (uses h0b = h0(2047), h1b = h1(2046)) ----
    {
        v2f d = bias1p, ee = (v2f){0.0f, 0.0f};
        d  = vfma(h0b0, wi1p0, d);
        ee = vfma(h0b1, wi1p1, ee);
        d  = vfma(h0b2, wi1p2, d);
        ee = vfma(h0b3, wi1p3, ee);
        d  = vfma(h0b4, wi1p4, d);
        ee = vfma(h1b0, wh1p0, ee);
        d  = vfma(h1b1, wh1p1, d);
        ee = vfma(h1b2, wh1p2, ee);
        d  = vfma(h1b3, wh1p3, d);
        ee = vfma(h1b4, wh1p4, ee);
        d = d + ee;
        const float e1x = __builtin_amdgcn_exp2f(d.x);
        const float e1y = __builtin_amdgcn_exp2f(d.y);
        const float n1A = fmaf(-2.0f, __builtin_amdgcn_rcpf(1.0f + e1x), 1.0f);
        const float n1B = fmaf(-2.0f, __builtin_amdgcn_rcpf(1.0f + e1y), 1.0f);
        out[ooffA] = n1A;
        out[ooffB] = n1B;
        h1b0 = qbcast<0>(n1A);
        h1b1 = qbcast<1>(n1A);
        h1b2 = qbcast<2>(n1A);
        h1b3 = qbcast<3>(n1A);
        h1b4 = n1B;
    }
#undef PAIR
#undef P0ONLY

    // h_n = [h0_final, h1_final] after out[T,B,H]; quad-dup stores benign
    float* hn = out + (size_t)SEQ_T * BATCH * HSZ;
    hn[(size_t)c * HSZ + 0] = h0b0;
    hn[(size_t)c * HSZ + 1] = h0b1;
    hn[(size_t)c * HSZ + 2] = h0b2;
    hn[(size_t)c * HSZ + 3] = h0b3;
    hn[(size_t)c * HSZ + 4] = h0b4;
    hn[hb1 + 0] = h1b0;
    hn[hb1 + 1] = h1b1;
    hn[hb1 + 2] = h1b2;
    hn[hb1 + 3] = h1b3;
    hn[hb1 + 4] = h1b4;
}

extern "C" void kernel_launch(void* const* d_in, const int* in_sizes, int n_in,
                              void* d_out, int out_size, void* d_ws, size_t ws_size,
                              hipStream_t stream) {
    // 4096 chains x 4 lanes = 16384 threads; 64-thread blocks -> 256 blocks,
    // one wave per CU across all 256 CUs.
    rnn2_swp<<<(BATCH * 4) / 64, 64, 0, stream>>>(
        (const float*)d_in[0], (const float*)d_in[1],
        (const float*)d_in[2], (const float*)d_in[3],
        (const float*)d_in[4], (const float*)d_in[5],
        (const float*)d_in[6], (const float*)d_in[7],
        (const float*)d_in[8], (const float*)d_in[9],
        (float*)d_out);
}

// Round 7
// 424.536 us; speedup vs baseline: 1.2605x; 1.0506x over previous
//
#include <hip/hip_runtime.h>

// 2-layer tanh RNN, T=2048, B=4096, I=3, H=5. f32 storage.
//
// R12: fit across R5..R11 shows a SOLO wave pays ~6-7 cy per issued
// instruction regardless of mix; W = instr/step x solo-issue cost, with
// the 5 VMEM ops/step (wave64 address-processing, nothing co-resident to
// overlap it) and the scalar tanh tail as the biggest line items.
// Diet, keeping R11's verified interleaved structure:
//  - 3 scalar x loads -> 1 global_load_dwordx3 (12B contiguous per step)
//  - pk slots re-paired (ja, ja+1) instead of (ja, 4): the tanh result
//    pair (u_ja, u_ja+1) stores with ONE global_store_dwordx2 at c*5+ja
//    (overlapping dup writes carry identical values). VMEM 5 -> 2.
//    Broadcast: units 0-3 from A slots (qp<0..3>), unit 4 from lane3's
//    B slot (qp<3> of n.y) = 5 DPP/layer.
//  - tanh tail packed: (1+e) via one v_pk_add, 1-2r via one v_pk_fma.
// Per-UNIT accumulation order and tanh formula are bit-identical to R11
// (only which lane computes a unit changed) -> absmax stays 0.00390625.

typedef float v2f  __attribute__((ext_vector_type(2)));
typedef float v2fu __attribute__((ext_vector_type(2), aligned(4)));
typedef float v3fu __attribute__((ext_vector_type(3), aligned(4)));

#define SEQ_T 2048
#define BATCH 4096
#define ISZ 3
#define HSZ 5
#define XSTRIDE (BATCH * ISZ)
#define OSTRIDE (BATCH * HSZ)

template<int K>
__device__ __forceinline__ float qbcast(float v) {
    return __int_as_float(__builtin_amdgcn_mov_dpp(
        __float_as_int(v), K * 0x55, 0xF, 0xF, false));
}
__device__ __forceinline__ v2f vsplat(float s) { return (v2f){s, s}; }
__device__ __forceinline__ v2f vfma(float s, v2f w, v2f a) {
    return __builtin_elementwise_fma(vsplat(s), w, a);  // v_pk_fma_f32
}

__global__ __launch_bounds__(64, 1)
void rnn2_diet(const float* __restrict__ x, const float* __restrict__ hx,
               const float* __restrict__ w_ih0, const float* __restrict__ w_hh0,
               const float* __restrict__ b_ih0, const float* __restrict__ b_hh0,
               const float* __restrict__ w_ih1, const float* __restrict__ w_hh1,
               const float* __restrict__ b_ih1, const float* __restrict__ b_hh1,
               float* __restrict__ out)
{
    const int tid = threadIdx.x;
    const int c   = (blockIdx.x * 64 + tid) >> 2;   // chain id, 0..4095
    const int ja  = tid & 3;                        // slot A = unit ja
    const int jb  = ja + 1;                         // slot B = unit ja+1
    const float S = 2.8853900817779268f;            // 2*log2(e)

    // ---- weight pairs (ja-row, jb-row), pre-scaled by S — all NAMED ----
    const v2f bias0p = (v2f){ S * (b_ih0[ja] + b_hh0[ja]), S * (b_ih0[jb] + b_hh0[jb]) };
    const v2f bias1p = (v2f){ S * (b_ih1[ja] + b_hh1[ja]), S * (b_ih1[jb] + b_hh1[jb]) };
#define LW(W, k, n)  (v2f){ S * W[ja * (n) + (k)], S * W[jb * (n) + (k)] }
    const v2f wi0p0 = LW(w_ih0, 0, ISZ), wi0p1 = LW(w_ih0, 1, ISZ), wi0p2 = LW(w_ih0, 2, ISZ);
    const v2f wh0p0 = LW(w_hh0, 0, HSZ), wh0p1 = LW(w_hh0, 1, HSZ), wh0p2 = LW(w_hh0, 2, HSZ),
              wh0p3 = LW(w_hh0, 3, HSZ), wh0p4 = LW(w_hh0, 4, HSZ);
    const v2f wi1p0 = LW(w_ih1, 0, HSZ), wi1p1 = LW(w_ih1, 1, HSZ), wi1p2 = LW(w_ih1, 2, HSZ),
              wi1p3 = LW(w_ih1, 3, HSZ), wi1p4 = LW(w_ih1, 4, HSZ);
    const v2f wh1p0 = LW(w_hh1, 0, HSZ), wh1p1 = LW(w_hh1, 1, HSZ), wh1p2 = LW(w_hh1, 2, HSZ),
              wh1p3 = LW(w_hh1, 3, HSZ), wh1p4 = LW(w_hh1, 4, HSZ);
#undef LW

    // ---- state: named scalars, full vectors on every lane ----
    float h0b0 = hx[(size_t)c * HSZ + 0], h0b1 = hx[(size_t)c * HSZ + 1],
          h0b2 = hx[(size_t)c * HSZ + 2], h0b3 = hx[(size_t)c * HSZ + 3],
          h0b4 = hx[(size_t)c * HSZ + 4];
    const size_t hb1 = (size_t)BATCH * HSZ + (size_t)c * HSZ;
    float h1b0 = hx[hb1 + 0], h1b1 = hx[hb1 + 1], h1b2 = hx[hb1 + 2],
          h1b3 = hx[hb1 + 3], h1b4 = hx[hb1 + 4];

    // ---- x pipeline: depth 8, 8 named v3 registers (dwordx3 loads) ----
    unsigned xoff = (unsigned)c * ISZ;
    v3fu x0 = *(const v3fu*)(x + xoff + 0*XSTRIDE);
    v3fu x1 = *(const v3fu*)(x + xoff + 1*XSTRIDE);
    v3fu x2 = *(const v3fu*)(x + xoff + 2*XSTRIDE);
    v3fu x3 = *(const v3fu*)(x + xoff + 3*XSTRIDE);
    v3fu x4 = *(const v3fu*)(x + xoff + 4*XSTRIDE);
    v3fu x5 = *(const v3fu*)(x + xoff + 5*XSTRIDE);
    v3fu x6 = *(const v3fu*)(x + xoff + 6*XSTRIDE);
    v3fu x7 = *(const v3fu*)(x + xoff + 7*XSTRIDE);
    xoff += 8 * XSTRIDE;

    unsigned ooff = (unsigned)c * HSZ + (unsigned)ja;  // dwordx2 dest

// PAIR: L0-dot(t) interleaved with L1-dot(t-1); both read h0b = h0(t-1).
// Packed tanh tails, 5 DPP bcast per layer, single dwordx2 store.
#define PAIR(XV, DOLOAD)                                                   \
    {                                                                      \
        const float xv0 = XV.x, xv1 = XV.y, xv2 = XV.z;                    \
        if (DOLOAD) {                                                      \
            XV = *(const v3fu*)(x + xoff);                                 \
            xoff += XSTRIDE;                                               \
        }                                                                  \
        v2f a = bias0p, cc = (v2f){0.0f, 0.0f};                            \
        v2f d = bias1p, ee = (v2f){0.0f, 0.0f};                            \
        a  = vfma(xv0,  wi0p0, a);                                         \
        d  = vfma(h0b0, wi1p0, d);                                         \
        cc = vfma(xv1,  wi0p1, cc);                                        \
        ee = vfma(h0b1, wi1p1, ee);                                        \
        a  = vfma(xv2,  wi0p2, a);                                         \
        d  = vfma(h0b2, wi1p2, d);                                         \
        cc = vfma(h0b0, wh0p0, cc);                                        \
        ee = vfma(h0b3, wi1p3, ee);                                        \
        a  = vfma(h0b1, wh0p1, a);                                         \
        d  = vfma(h0b4, wi1p4, d);                                         \
        cc = vfma(h0b2, wh0p2, cc);                                        \
        ee = vfma(h1b0, wh1p0, ee);                                        \
        a  = vfma(h0b3, wh0p3, a);                                         \
        d  = vfma(h1b1, wh1p1, d);                                         \
        cc = vfma(h0b4, wh0p4, cc);                                        \
        ee = vfma(h1b2, wh1p2, ee);                                        \
        a = a + cc;                                                        \
        d  = vfma(h1b3, wh1p3, d);                                         \
        ee = vfma(h1b4, wh1p4, ee);                                        \
        v2f e0;                                                            \
        e0.x = __builtin_amdgcn_exp2f(a.x);                                \
        e0.y = __builtin_amdgcn_exp2f(a.y);                                \
        d = d + ee;                                                        \
        v2f e1;                                                            \
        e1.x = __builtin_amdgcn_exp2f(d.x);                                \
        e1.y = __builtin_amdgcn_exp2f(d.y);                                \
        const v2f p0 = e0 + vsplat(1.0f);                                  \
        const v2f p1 = e1 + vsplat(1.0f);                                  \
        v2f r0;                                                            \
        r0.x = __builtin_amdgcn_rcpf(p0.x);                                \
        r0.y = __builtin_amdgcn_rcpf(p0.y);                                \
        v2f r1;                                                            \
        r1.x = __builtin_amdgcn_rcpf(p1.x);                                \
        r1.y = __builtin_amdgcn_rcpf(p1.y);                                \
        const v2f n0 = __builtin_elementwise_fma(vsplat(-2.0f), r0, vsplat(1.0f)); \
        const v2f n1 = __builtin_elementwise_fma(vsplat(-2.0f), r1, vsplat(1.0f)); \
        h0b0 = qbcast<0>(n0.x);                                            \
        h0b1 = qbcast<1>(n0.x);                                            \
        h0b2 = qbcast<2>(n0.x);                                            \
        h0b3 = qbcast<3>(n0.x);                                            \
        h0b4 = qbcast<3>(n0.y);                                            \
        *(v2fu*)(out + ooff) = n1;                                         \
        ooff += OSTRIDE;                                                   \
        h1b0 = qbcast<0>(n1.x);                                            \
        h1b1 = qbcast<1>(n1.x);                                            \
        h1b2 = qbcast<2>(n1.x);                                            \
        h1b3 = qbcast<3>(n1.x);                                            \
        h1b4 = qbcast<3>(n1.y);                                            \
    }

// L0-only (pipeline prologue, step 0)
#define P0ONLY(XV)                                                         \
    {                                                                      \
        const float xv0 = XV.x, xv1 = XV.y, xv2 = XV.z;                    \
        XV = *(const v3fu*)(x + xoff);                                     \
        xoff += XSTRIDE;                                                   \
        v2f a = bias0p, cc = (v2f){0.0f, 0.0f};                            \
        a  = vfma(xv0,  wi0p0, a);                                         \
        cc = vfma(xv1,  wi0p1, cc);                                        \
        a  = vfma(xv2,  wi0p2, a);                                         \
        cc = vfma(h0b0, wh0p0, cc);                                        \
        a  = vfma(h0b1, wh0p1, a);                                         \
        cc = vfma(h0b2, wh0p2, cc);                                        \
        a  = vfma(h0b3, wh0p3, a);                                         \
        cc = vfma(h0b4, wh0p4, cc);                                        \
        a = a + cc;                                                        \
        v2f e0;                                                            \
        e0.x = __builtin_amdgcn_exp2f(a.x);                                \
        e0.y = __builtin_amdgcn_exp2f(a.y);                                \
        const v2f p0 = e0 + vsplat(1.0f);                                  \
        v2f r0;                                                            \
        r0.x = __builtin_amdgcn_rcpf(p0.x);                                \
        r0.y = __builtin_amdgcn_rcpf(p0.y);                                \
        const v2f n0 = __builtin_elementwise_fma(vsplat(-2.0f), r0, vsplat(1.0f)); \
        h0b0 = qbcast<0>(n0.x);                                            \
        h0b1 = qbcast<1>(n0.x);                                            \
        h0b2 = qbcast<2>(n0.x);                                            \
        h0b3 = qbcast<3>(n0.x);                                            \
        h0b4 = qbcast<3>(n0.y);                                            \
    }

    // ---- prologue: P0(0); then pairs P0(1..7)|P1(0..6), all refilling ----
    P0ONLY(x0)
    PAIR(x1, 1)
    PAIR(x2, 1)
    PAIR(x3, 1)
    PAIR(x4, 1)
    PAIR(x5, 1)
    PAIR(x6, 1)
    PAIR(x7, 1)

    // ---- steady: blocks 1..254, refilling 8 steps ahead ----
    for (int blk = 1; blk < SEQ_T / 8 - 1; ++blk) {
        PAIR(x0, 1)
        PAIR(x1, 1)
        PAIR(x2, 1)
        PAIR(x3, 1)
        PAIR(x4, 1)
        PAIR(x5, 1)
        PAIR(x6, 1)
        PAIR(x7, 1)
    }

    // ---- final block 255: steps 2040..2047, no refill ----
    PAIR(x0, 0)
    PAIR(x1, 0)
    PAIR(x2, 0)
    PAIR(x3, 0)
    PAIR(x4, 0)
    PAIR(x5, 0)
    PAIR(x6, 0)
    PAIR(x7, 0)

    // ---- epilogue: P1(2047) (uses h0b = h0(2047), h1b = h1(2046)) ----
    {
        v2f d = bias1p, ee = (v2f){0.0f, 0.0f};
        d  = vfma(h0b0, wi1p0, d);
        ee = vfma(h0b1, wi1p1, ee);
        d  = vfma(h0b2, wi1p2, d);
        ee = vfma(h0b3, wi1p3, ee);
        d  = vfma(h0b4, wi1p4, d);
        ee = vfma(h1b0, wh1p0, ee);
        d  = vfma(h1b1, wh1p1, d);
        ee = vfma(h1b2, wh1p2, ee);
        d  = vfma(h1b3, wh1p3, d);
        ee = vfma(h1b4, wh1p4, ee);
        d = d + ee;
        v2f e1;
        e1.x = __builtin_amdgcn_exp2f(d.x);
        e1.y = __builtin_amdgcn_exp2f(d.y);
        const v2f p1 = e1 + vsplat(1.0f);
        v2f r1;
        r1.x = __builtin_amdgcn_rcpf(p1.x);
        r1.y = __builtin_amdgcn_rcpf(p1.y);
        const v2f n1 = __builtin_elementwise_fma(vsplat(-2.0f), r1, vsplat(1.0f));
        *(v2fu*)(out + ooff) = n1;
        h1b0 = qbcast<0>(n1.x);
        h1b1 = qbcast<1>(n1.x);
        h1b2 = qbcast<2>(n1.x);
        h1b3 = qbcast<3>(n1.x);
        h1b4 = qbcast<3>(n1.y);
    }
#undef PAIR
#undef P0ONLY

    // h_n = [h0_final, h1_final] after out[T,B,H]; quad-dup stores benign
    float* hn = out + (size_t)SEQ_T * BATCH * HSZ;
    hn[(size_t)c * HSZ + 0] = h0b0;
    hn[(size_t)c * HSZ + 1] = h0b1;
    hn[(size_t)c * HSZ + 2] = h0b2;
    hn[(size_t)c * HSZ + 3] = h0b3;
    hn[(size_t)c * HSZ + 4] = h0b4;
    hn[hb1 + 0] = h1b0;
    hn[hb1 + 1] = h1b1;
    hn[hb1 + 2] = h1b2;
    hn[hb1 + 3] = h1b3;
    hn[hb1 + 4] = h1b4;
}

extern "C" void kernel_launch(void* const* d_in, const int* in_sizes, int n_in,
                              void* d_out, int out_size, void* d_ws, size_t ws_size,
                              hipStream_t stream) {
    // 4096 chains x 4 lanes = 16384 threads; 64-thread blocks -> 256 blocks,
    // one wave per CU across all 256 CUs.
    rnn2_diet<<<(BATCH * 4) / 64, 64, 0, stream>>>(
        (const float*)d_in[0], (const float*)d_in[1],
        (const float*)d_in[2], (const float*)d_in[3],
        (const float*)d_in[4], (const float*)d_in[5],
        (const float*)d_in[6], (const float*)d_in[7],
        (const float*)d_in[8], (const float*)d_in[9],
        (float*)d_out);
}